// Round 1
// baseline (1811.937 us; speedup 1.0000x reference)
//
#include <hip/hip_runtime.h>
#include <hip/hip_bf16.h>

#define N_NODES 50000
#define N_EDGES 800000
#define D       64
#define HID     256
#define DIN     128   // 2*D
#define NB      32    // nodes per block in MLP kernel

// ---------------------------------------------------------------------------
// Scatter: agg[senders[e]] += edges[e]; agg[receivers[e]] += edges[e]
// 16 threads per edge, one float4 chunk each. Coalesced 256B row reads.
// ---------------------------------------------------------------------------
__global__ __launch_bounds__(256) void scatter_kernel(
    const float* __restrict__ edges,
    const int* __restrict__ senders,
    const int* __restrict__ receivers,
    float* __restrict__ agg)
{
    int tid = blockIdx.x * 256 + threadIdx.x;
    int e = tid >> 4;          // edge index
    int c = (tid & 15) << 2;   // float chunk offset 0,4,...,60
    if (e >= N_EDGES) return;

    const float4 v = *reinterpret_cast<const float4*>(edges + (long)e * D + c);
    int s = senders[e] * D + c;
    int r = receivers[e] * D + c;

    atomicAdd(&agg[s + 0], v.x);
    atomicAdd(&agg[s + 1], v.y);
    atomicAdd(&agg[s + 2], v.z);
    atomicAdd(&agg[s + 3], v.w);
    atomicAdd(&agg[r + 0], v.x);
    atomicAdd(&agg[r + 1], v.y);
    atomicAdd(&agg[r + 2], v.z);
    atomicAdd(&agg[r + 3], v.w);
}

// ---------------------------------------------------------------------------
// Fused MLP: out = relu([agg | nodes] @ W1 + b1) @ W2 + b2
// 256 threads = 256 hidden units; NB=32 nodes per block.
// Phase 1: thread t holds W1 column t in 128 VGPRs; x-values are read with
//          wave-uniform addresses (-> scalar loads), inner loop is pure fmac.
// Phase 2: h staged in LDS [NB][HID]; thread t -> (ng = t>>6, d = t&63),
//          W2 read coalesced, lds_h reads wave-uniform (broadcast).
// ---------------------------------------------------------------------------
__global__ __launch_bounds__(256, 2) void mlp_kernel(
    const float* __restrict__ agg,     // [N, 64]
    const float* __restrict__ nodes,   // [N, 64]
    const float* __restrict__ W1,      // [128, 256]
    const float* __restrict__ b1,      // [256]
    const float* __restrict__ W2,      // [256, 64]
    const float* __restrict__ b2,      // [64]
    float* __restrict__ out)           // [N, 64]
{
    __shared__ __align__(16) float lds_h[NB][HID];   // 32 KB

    const int t = threadIdx.x;
    const int node0 = blockIdx.x * NB;

    // W1 column t -> registers (coalesced across lanes; L2-resident)
    float w1c[DIN];
    #pragma unroll
    for (int k = 0; k < DIN; ++k) w1c[k] = W1[k * HID + t];
    const float bias1 = b1[t];

    // ---- Phase 1: h[n][t] = relu(x[n] . W1[:,t] + b1[t]) ----
    for (int n = 0; n < NB; ++n) {
        const int node = node0 + n;
        float acc = bias1;
        if (node < N_NODES) {
            const float* __restrict__ arow = agg   + (long)node * D;
            const float* __restrict__ nrow = nodes + (long)node * D;
            #pragma unroll
            for (int k = 0; k < D; ++k) acc += w1c[k] * arow[k];
            #pragma unroll
            for (int k = 0; k < D; ++k) acc += w1c[D + k] * nrow[k];
        }
        lds_h[n][t] = fmaxf(acc, 0.0f);
    }
    __syncthreads();

    // ---- Phase 2: out[n][d] = h[n] . W2[:,d] + b2[d] ----
    const int d  = t & 63;
    const int ng = t >> 6;   // 0..3 -> handles n = ng + 4*i

    float acc2[8];
    #pragma unroll
    for (int i = 0; i < 8; ++i) acc2[i] = 0.0f;

    for (int j = 0; j < HID; j += 4) {
        const float w0 = W2[(j + 0) * D + d];
        const float w1 = W2[(j + 1) * D + d];
        const float w2 = W2[(j + 2) * D + d];
        const float w3 = W2[(j + 3) * D + d];
        #pragma unroll
        for (int i = 0; i < 8; ++i) {
            const int n = ng + 4 * i;
            const float4 h4 = *reinterpret_cast<const float4*>(&lds_h[n][j]);
            acc2[i] += w0 * h4.x + w1 * h4.y + w2 * h4.z + w3 * h4.w;
        }
    }

    const float bias2 = b2[d];
    #pragma unroll
    for (int i = 0; i < 8; ++i) {
        const int n = ng + 4 * i;
        const int node = node0 + n;
        if (node < N_NODES) out[(long)node * D + d] = acc2[i] + bias2;
    }
}

// ---------------------------------------------------------------------------
extern "C" void kernel_launch(void* const* d_in, const int* in_sizes, int n_in,
                              void* d_out, int out_size, void* d_ws, size_t ws_size,
                              hipStream_t stream)
{
    const float* nodes     = (const float*)d_in[0];
    const float* edges     = (const float*)d_in[1];
    const int*   senders   = (const int*)  d_in[2];
    const int*   receivers = (const int*)  d_in[3];
    const float* W1        = (const float*)d_in[4];
    const float* b1        = (const float*)d_in[5];
    const float* W2        = (const float*)d_in[6];
    const float* b2        = (const float*)d_in[7];
    float* out = (float*)d_out;

    float* agg = (float*)d_ws;                       // [N_NODES, D] = 12.8 MB
    const size_t agg_bytes = (size_t)N_NODES * D * sizeof(float);

    // ws is re-poisoned to 0xAA before every call -> zero it every call.
    hipMemsetAsync(agg, 0, agg_bytes, stream);

    // Scatter: 800000 edges * 16 threads = 12.8M threads
    const int scatter_blocks = (N_EDGES * 16) / 256;  // 50000, exact
    scatter_kernel<<<scatter_blocks, 256, 0, stream>>>(edges, senders, receivers, agg);

    // Fused MLP: 32 nodes per block
    const int mlp_blocks = (N_NODES + NB - 1) / NB;   // 1563
    mlp_kernel<<<mlp_blocks, 256, 0, stream>>>(agg, nodes, W1, b1, W2, b2, out);
}

// Round 3
// 855.449 us; speedup vs baseline: 2.1181x; 2.1181x over previous
//
#include <hip/hip_runtime.h>
#include <hip/hip_bf16.h>

#define N_NODES 50000
#define N_EDGES 800000
#define D       64
#define HID     256
#define DIN     128   // 2*D
#define NB      32    // nodes per block in MLP kernel

// ---------------------------------------------------------------------------
// CSR build, pass 1: degree[n] = #edges incident as sender + as receiver
// ---------------------------------------------------------------------------
__global__ __launch_bounds__(256) void degree_kernel(
    const int* __restrict__ senders,
    const int* __restrict__ receivers,
    int* __restrict__ deg)
{
    int e = blockIdx.x * 256 + threadIdx.x;
    if (e < N_EDGES) {
        atomicAdd(&deg[senders[e]],   1);
        atomicAdd(&deg[receivers[e]], 1);
    }
}

// ---------------------------------------------------------------------------
// CSR build, pass 2: exclusive scan of deg -> offs[50001]; also init cursor.
// Single block, 1024 threads, 49 chunks with running carry.
// ---------------------------------------------------------------------------
__global__ __launch_bounds__(1024) void scan_kernel(
    const int* __restrict__ deg,
    int* __restrict__ offs,
    int* __restrict__ cursor)
{
    __shared__ int wsum[16];
    __shared__ int chunk_total;
    const int t = threadIdx.x, lane = t & 63, w = t >> 6;
    int carry = 0;
    for (int base = 0; base < N_NODES; base += 1024) {
        int i = base + t;
        int v = (i < N_NODES) ? deg[i] : 0;
        int x = v;                       // inclusive wave scan
        #pragma unroll
        for (int off = 1; off < 64; off <<= 1) {
            int y = __shfl_up(x, off, 64);
            if (lane >= off) x += y;
        }
        if (lane == 63) wsum[w] = x;
        __syncthreads();
        if (t < 16) {                    // scan the 16 wave totals
            int s_ = wsum[t];
            #pragma unroll
            for (int off = 1; off < 16; off <<= 1) {
                int y = __shfl_up(s_, off, 64);
                if (t >= off) s_ += y;
            }
            wsum[t] = s_;
            if (t == 15) chunk_total = s_;
        }
        __syncthreads();
        int pre  = carry + (w > 0 ? wsum[w - 1] : 0);
        int excl = pre + (x - v);
        if (i < N_NODES) { offs[i] = excl; cursor[i] = excl; }
        carry += chunk_total;
        __syncthreads();                 // wsum/chunk_total reused next iter
    }
    if (t == 0) offs[N_NODES] = carry;   // = 2*N_EDGES
}

// ---------------------------------------------------------------------------
// CSR build, pass 3: fill combined incident-edge lists.
// ---------------------------------------------------------------------------
__global__ __launch_bounds__(256) void fill_kernel(
    const int* __restrict__ senders,
    const int* __restrict__ receivers,
    int* __restrict__ cursor,
    int* __restrict__ eidx)
{
    int e = blockIdx.x * 256 + threadIdx.x;
    if (e < N_EDGES) {
        int p = atomicAdd(&cursor[senders[e]],   1); eidx[p] = e;
        int q = atomicAdd(&cursor[receivers[e]], 1); eidx[q] = e;
    }
}

// ---------------------------------------------------------------------------
// Gather: one wave per node; lane d sums edges[eid][d] over incident edges.
// Each edge row read = one coalesced 256B load across the wave.
// ---------------------------------------------------------------------------
__global__ __launch_bounds__(256) void gather_kernel(
    const float* __restrict__ edges,
    const int* __restrict__ offs,
    const int* __restrict__ eidx,
    float* __restrict__ agg)
{
    const int node = blockIdx.x * 4 + (threadIdx.x >> 6);
    const int lane = threadIdx.x & 63;
    if (node >= N_NODES) return;

    const int beg = offs[node], end = offs[node + 1];
    float acc = 0.0f;
    int i = beg;
    for (; i + 4 <= end; i += 4) {       // 4-deep ILP to hide HBM latency
        int e0 = eidx[i], e1 = eidx[i+1], e2 = eidx[i+2], e3 = eidx[i+3];
        float v0 = edges[(size_t)e0 * D + lane];
        float v1 = edges[(size_t)e1 * D + lane];
        float v2 = edges[(size_t)e2 * D + lane];
        float v3 = edges[(size_t)e3 * D + lane];
        acc += (v0 + v1) + (v2 + v3);
    }
    for (; i < end; ++i)
        acc += edges[(size_t)eidx[i] * D + lane];
    agg[(size_t)node * D + lane] = acc;
}

// ---------------------------------------------------------------------------
// Fallback scatter (used only if ws too small for CSR): as round 1.
// ---------------------------------------------------------------------------
__global__ __launch_bounds__(256) void scatter_kernel(
    const float* __restrict__ edges,
    const int* __restrict__ senders,
    const int* __restrict__ receivers,
    float* __restrict__ agg)
{
    int tid = blockIdx.x * 256 + threadIdx.x;
    int e = tid >> 4;
    int c = (tid & 15) << 2;
    if (e >= N_EDGES) return;
    const float4 v = *reinterpret_cast<const float4*>(edges + (long)e * D + c);
    int s = senders[e] * D + c;
    int r = receivers[e] * D + c;
    atomicAdd(&agg[s + 0], v.x); atomicAdd(&agg[s + 1], v.y);
    atomicAdd(&agg[s + 2], v.z); atomicAdd(&agg[s + 3], v.w);
    atomicAdd(&agg[r + 0], v.x); atomicAdd(&agg[r + 1], v.y);
    atomicAdd(&agg[r + 2], v.z); atomicAdd(&agg[r + 3], v.w);
}

// ---------------------------------------------------------------------------
// Fused MLP: out = relu([agg | nodes] @ W1 + b1) @ W2 + b2
// Phase 1: x rows staged in LDS (broadcast ds_read_b128), W1 col per thread
//          in 128 VGPRs, 4 rotating accumulators to break the fmac chain.
// Phase 2: h in LDS; thread (ng,d) does coalesced W2 reads + LDS broadcasts.
// ---------------------------------------------------------------------------
__global__ __launch_bounds__(256, 2) void mlp_kernel(
    const float* __restrict__ agg,     // [N, 64]
    const float* __restrict__ nodes,   // [N, 64]
    const float* __restrict__ W1,      // [128, 256]
    const float* __restrict__ b1,      // [256]
    const float* __restrict__ W2,      // [256, 64]
    const float* __restrict__ b2,      // [64]
    float* __restrict__ out)           // [N, 64]
{
    __shared__ __align__(16) float x_lds[NB][DIN];   // 16 KB
    __shared__ __align__(16) float h_lds[NB][HID];   // 32 KB

    const int t = threadIdx.x;
    const int node0 = blockIdx.x * NB;

    // Cooperative x staging: 1024 float4s, coalesced
    for (int f = t; f < NB * DIN / 4; f += 256) {
        int n = f >> 5;          // 32 float4 per row
        int c = f & 31;
        int node = node0 + n;
        float4 v = make_float4(0.f, 0.f, 0.f, 0.f);
        if (node < N_NODES) {
            const float* src = (c < 16) ? (agg   + (size_t)node * D + c * 4)
                                        : (nodes + (size_t)node * D + (c - 16) * 4);
            v = *reinterpret_cast<const float4*>(src);
        }
        *reinterpret_cast<float4*>(&x_lds[n][c * 4]) = v;
    }

    // W1 column t -> 128 VGPRs (coalesced across lanes, L2-resident)
    float w1c[DIN];
    #pragma unroll
    for (int k = 0; k < DIN; ++k) w1c[k] = W1[(size_t)k * HID + t];
    const float bias1 = b1[t];
    __syncthreads();

    // ---- Phase 1 ----
    for (int n = 0; n < NB; ++n) {
        const float4* xr = reinterpret_cast<const float4*>(x_lds[n]);
        float acc[4] = {0.f, 0.f, 0.f, 0.f};
        #pragma unroll
        for (int k4 = 0; k4 < 32; ++k4) {
            float4 x = xr[k4];
            float p = w1c[4*k4 + 0] * x.x + w1c[4*k4 + 1] * x.y;
            float q = w1c[4*k4 + 2] * x.z + w1c[4*k4 + 3] * x.w;
            acc[k4 & 3] += p + q;
        }
        h_lds[n][t] = fmaxf(bias1 + ((acc[0] + acc[1]) + (acc[2] + acc[3])), 0.0f);
    }
    __syncthreads();

    // ---- Phase 2 ----
    const int d  = t & 63;
    const int ng = t >> 6;

    float acc2[8];
    #pragma unroll
    for (int i = 0; i < 8; ++i) acc2[i] = 0.0f;

    for (int j = 0; j < HID; j += 4) {
        const float w0 = W2[(j + 0) * D + d];
        const float w1 = W2[(j + 1) * D + d];
        const float w2 = W2[(j + 2) * D + d];
        const float w3 = W2[(j + 3) * D + d];
        #pragma unroll
        for (int i = 0; i < 8; ++i) {
            const int n = ng + 4 * i;
            const float4 h4 = *reinterpret_cast<const float4*>(&h_lds[n][j]);
            acc2[i] += w0 * h4.x + w1 * h4.y + w2 * h4.z + w3 * h4.w;
        }
    }

    const float bias2 = b2[d];
    #pragma unroll
    for (int i = 0; i < 8; ++i) {
        const int n = ng + 4 * i;
        const int node = node0 + n;
        if (node < N_NODES) out[(size_t)node * D + d] = acc2[i] + bias2;
    }
}

// ---------------------------------------------------------------------------
extern "C" void kernel_launch(void* const* d_in, const int* in_sizes, int n_in,
                              void* d_out, int out_size, void* d_ws, size_t ws_size,
                              hipStream_t stream)
{
    const float* nodes     = (const float*)d_in[0];
    const float* edges     = (const float*)d_in[1];
    const int*   senders   = (const int*)  d_in[2];
    const int*   receivers = (const int*)  d_in[3];
    const float* W1        = (const float*)d_in[4];
    const float* b1        = (const float*)d_in[5];
    const float* W2        = (const float*)d_in[6];
    const float* b2        = (const float*)d_in[7];
    float* out = (float*)d_out;

    // Workspace layout
    float* agg    = (float*)d_ws;                    // 3,200,000 f32 = 12.8 MB
    int*   ibase  = (int*)d_ws + 3200000;
    int*   deg    = ibase;                           // 50,000
    int*   offs   = deg + N_NODES;                   // 50,001
    int*   cursor = offs + N_NODES + 1;              // 50,000
    int*   eidx   = cursor + N_NODES;                // 1,600,000
    const size_t need_bytes = (3200000 + 50000 + 50001 + 50000 + 1600000) * 4ull;

    if (ws_size >= need_bytes) {
        // ---- CSR counting-sort path ----
        hipMemsetAsync(deg, 0, N_NODES * sizeof(int), stream);

        const int eb = (N_EDGES + 255) / 256;        // 3125
        degree_kernel<<<eb, 256, 0, stream>>>(senders, receivers, deg);
        scan_kernel<<<1, 1024, 0, stream>>>(deg, offs, cursor);
        fill_kernel<<<eb, 256, 0, stream>>>(senders, receivers, cursor, eidx);

        const int gather_blocks = (N_NODES + 3) / 4;   // 4 waves/block, 1 node/wave
        gather_kernel<<<gather_blocks, 256, 0, stream>>>(edges, offs, eidx, agg);
    } else {
        // ---- Fallback: atomic scatter (round-1 path) ----
        hipMemsetAsync(agg, 0, (size_t)N_NODES * D * sizeof(float), stream);
        scatter_kernel<<<(N_EDGES * 16) / 256, 256, 0, stream>>>(edges, senders, receivers, agg);
    }

    mlp_kernel<<<(N_NODES + NB - 1) / NB, 256, 0, stream>>>(
        agg, nodes, W1, b1, W2, b2, out);
}

// Round 4
// 663.773 us; speedup vs baseline: 2.7298x; 1.2888x over previous
//
#include <hip/hip_runtime.h>
#include <hip/hip_bf16.h>

#define N_NODES 50000
#define N_EDGES 800000
#define D       64
#define HID     256
#define DIN     128   // 2*D
#define NB      32    // nodes per block in fallback fused MLP

#define MB1     64    // nodes per block, gemm1
#define KC1     32    // k-chunk, gemm1
#define MB2     64    // nodes per block, gemm2
#define KC2     32    // k-chunk, gemm2

// ---------------------------------------------------------------------------
// CSR pass 1: degree
// ---------------------------------------------------------------------------
__global__ __launch_bounds__(256) void degree_kernel(
    const int* __restrict__ senders,
    const int* __restrict__ receivers,
    int* __restrict__ deg)
{
    int e = blockIdx.x * 256 + threadIdx.x;
    if (e < N_EDGES) {
        atomicAdd(&deg[senders[e]],   1);
        atomicAdd(&deg[receivers[e]], 1);
    }
}

// ---------------------------------------------------------------------------
// Scan stage 1: per-block sums of deg (1024 ints per block via int4)
// ---------------------------------------------------------------------------
__global__ __launch_bounds__(256) void scan_bsum_kernel(
    const int* __restrict__ deg, int* __restrict__ bsum)
{
    __shared__ int ws[4];
    const int t = threadIdx.x;
    const int i4 = blockIdx.x * 256 + t;
    int s = 0;
    if (i4 < N_NODES / 4) {
        int4 dv = reinterpret_cast<const int4*>(deg)[i4];
        s = dv.x + dv.y + dv.z + dv.w;
    }
    #pragma unroll
    for (int off = 32; off; off >>= 1) s += __shfl_down(s, off, 64);
    if ((t & 63) == 0) ws[t >> 6] = s;
    __syncthreads();
    if (t == 0) bsum[blockIdx.x] = ws[0] + ws[1] + ws[2] + ws[3];
}

// ---------------------------------------------------------------------------
// Scan stage 2: exclusive scan of 49 block sums (single wave)
// ---------------------------------------------------------------------------
__global__ __launch_bounds__(64) void scan_boff_kernel(
    const int* __restrict__ bsum, int* __restrict__ boff,
    int* __restrict__ offs_last, int nblocks)
{
    const int t = threadIdx.x;
    int v = (t < nblocks) ? bsum[t] : 0;
    int x = v;
    #pragma unroll
    for (int off = 1; off < 64; off <<= 1) {
        int y = __shfl_up(x, off, 64);
        if (t >= off) x += y;
    }
    if (t < nblocks) boff[t] = x - v;
    if (t == nblocks - 1) offs_last[0] = x;   // offs[N_NODES] = 2*N_EDGES
}

// ---------------------------------------------------------------------------
// Scan stage 3: per-block rescan + boff -> offs, cursor (int4 I/O)
// ---------------------------------------------------------------------------
__global__ __launch_bounds__(256) void scan_write_kernel(
    const int* __restrict__ deg, const int* __restrict__ boff,
    int* __restrict__ offs, int* __restrict__ cursor)
{
    __shared__ int wsum[4];
    const int t = threadIdx.x, lane = t & 63, w = t >> 6;
    const int i4 = blockIdx.x * 256 + t;
    int4 dv = make_int4(0, 0, 0, 0);
    if (i4 < N_NODES / 4) dv = reinterpret_cast<const int4*>(deg)[i4];
    const int s = dv.x + dv.y + dv.z + dv.w;
    int x = s;
    #pragma unroll
    for (int off = 1; off < 64; off <<= 1) {
        int y = __shfl_up(x, off, 64);
        if (lane >= off) x += y;
    }
    if (lane == 63) wsum[w] = x;
    __syncthreads();
    int wpre = 0;
    #pragma unroll
    for (int i = 0; i < 4; ++i) if (i < w) wpre += wsum[i];
    const int base = boff[blockIdx.x] + wpre + (x - s);
    int4 o;
    o.x = base; o.y = base + dv.x; o.z = o.y + dv.y; o.w = o.z + dv.z;
    if (i4 < N_NODES / 4) {
        reinterpret_cast<int4*>(offs)[i4]   = o;
        reinterpret_cast<int4*>(cursor)[i4] = o;
    }
}

// ---------------------------------------------------------------------------
// CSR pass 3: fill incident-edge lists
// ---------------------------------------------------------------------------
__global__ __launch_bounds__(256) void fill_kernel(
    const int* __restrict__ senders,
    const int* __restrict__ receivers,
    int* __restrict__ cursor,
    int* __restrict__ eidx)
{
    int e = blockIdx.x * 256 + threadIdx.x;
    if (e < N_EDGES) {
        int p = atomicAdd(&cursor[senders[e]],   1); eidx[p] = e;
        int q = atomicAdd(&cursor[receivers[e]], 1); eidx[q] = e;
    }
}

// ---------------------------------------------------------------------------
// Gather: one wave per node, lane = feature; 8-deep ILP
// ---------------------------------------------------------------------------
__global__ __launch_bounds__(256) void gather_kernel(
    const float* __restrict__ edges,
    const int* __restrict__ offs,
    const int* __restrict__ eidx,
    float* __restrict__ agg)
{
    const int node = blockIdx.x * 4 + (threadIdx.x >> 6);
    const int lane = threadIdx.x & 63;
    if (node >= N_NODES) return;

    const int beg = offs[node], end = offs[node + 1];
    float a0 = 0.f, a1 = 0.f;
    int i = beg;
    for (; i + 8 <= end; i += 8) {
        int e0 = eidx[i],   e1 = eidx[i+1], e2 = eidx[i+2], e3 = eidx[i+3];
        int e4 = eidx[i+4], e5 = eidx[i+5], e6 = eidx[i+6], e7 = eidx[i+7];
        float v0 = edges[(size_t)e0 * D + lane];
        float v1 = edges[(size_t)e1 * D + lane];
        float v2 = edges[(size_t)e2 * D + lane];
        float v3 = edges[(size_t)e3 * D + lane];
        float v4 = edges[(size_t)e4 * D + lane];
        float v5 = edges[(size_t)e5 * D + lane];
        float v6 = edges[(size_t)e6 * D + lane];
        float v7 = edges[(size_t)e7 * D + lane];
        a0 += (v0 + v1) + (v2 + v3);
        a1 += (v4 + v5) + (v6 + v7);
    }
    for (; i < end; ++i) a0 += edges[(size_t)eidx[i] * D + lane];
    agg[(size_t)node * D + lane] = a0 + a1;
}

// ---------------------------------------------------------------------------
// GEMM1: h = relu([agg|nodes] @ W1 + b1) -> hbuf [N][256] f32
// 256 thr, 64-node tile; thread (gn=t>>5, gj=t&31) owns 8 nodes x 8 cols
// (cols gj+32c -> conflict-free b32 W reads, coalesced h stores).
// ---------------------------------------------------------------------------
__global__ __launch_bounds__(256, 2) void gemm1_kernel(
    const float* __restrict__ agg,
    const float* __restrict__ nodes,
    const float* __restrict__ W1,     // [128][256]
    const float* __restrict__ b1,     // [256]
    float* __restrict__ hbuf)         // [N][256]
{
    __shared__ __align__(16) float xs[MB1][DIN + 4];   // 64x132 = 33.8KB
    __shared__ __align__(16) float wls[KC1][HID];      // 32x256 = 32KB

    const int t = threadIdx.x;
    const int node0 = blockIdx.x * MB1;
    const int gn = t >> 5;     // rows 8gn..8gn+7
    const int gj = t & 31;     // cols gj+32c, c=0..7

    // stage x = [agg row | nodes row], zero-filled past N
    for (int f = t; f < MB1 * 32; f += 256) {
        int n = f >> 5, c = f & 31;
        int node = node0 + n;
        float4 v = make_float4(0.f, 0.f, 0.f, 0.f);
        if (node < N_NODES)
            v = (c < 16) ? reinterpret_cast<const float4*>(agg   + (size_t)node * D)[c]
                         : reinterpret_cast<const float4*>(nodes + (size_t)node * D)[c - 16];
        *reinterpret_cast<float4*>(&xs[n][c * 4]) = v;
    }

    float acc[8][8];
    #pragma unroll
    for (int i = 0; i < 8; ++i)
        #pragma unroll
        for (int c = 0; c < 8; ++c) acc[i][c] = 0.f;

    for (int kc = 0; kc < DIN; kc += KC1) {
        __syncthreads();
        // stage W1 chunk [32][256]
        for (int f = t; f < KC1 * 64; f += 256) {
            int kk = f >> 6, c = f & 63;
            *reinterpret_cast<float4*>(&wls[kk][c * 4]) =
                reinterpret_cast<const float4*>(W1 + (size_t)(kc + kk) * HID)[c];
        }
        __syncthreads();

        #pragma unroll
        for (int k4 = 0; k4 < KC1; k4 += 4) {
            float4 xv[8];
            #pragma unroll
            for (int i = 0; i < 8; ++i)
                xv[i] = *reinterpret_cast<const float4*>(&xs[8 * gn + i][kc + k4]);
            float wv[4][8];
            #pragma unroll
            for (int kk = 0; kk < 4; ++kk)
                #pragma unroll
                for (int c = 0; c < 8; ++c) wv[kk][c] = wls[k4 + kk][gj + 32 * c];
            #pragma unroll
            for (int i = 0; i < 8; ++i)
                #pragma unroll
                for (int c = 0; c < 8; ++c) {
                    acc[i][c] = fmaf(xv[i].x, wv[0][c], acc[i][c]);
                    acc[i][c] = fmaf(xv[i].y, wv[1][c], acc[i][c]);
                    acc[i][c] = fmaf(xv[i].z, wv[2][c], acc[i][c]);
                    acc[i][c] = fmaf(xv[i].w, wv[3][c], acc[i][c]);
                }
        }
    }

    float bb[8];
    #pragma unroll
    for (int c = 0; c < 8; ++c) bb[c] = b1[gj + 32 * c];
    #pragma unroll
    for (int i = 0; i < 8; ++i) {
        const int node = node0 + 8 * gn + i;
        if (node < N_NODES) {
            #pragma unroll
            for (int c = 0; c < 8; ++c)
                hbuf[(size_t)node * HID + gj + 32 * c] = fmaxf(acc[i][c] + bb[c], 0.f);
        }
    }
}

// ---------------------------------------------------------------------------
// GEMM2: out = hbuf @ W2 + b2
// 256 thr, 64-node tile; thread (tn=t>>4, td=t&15) owns 4 nodes x 4 cols.
// ---------------------------------------------------------------------------
__global__ __launch_bounds__(256, 4) void gemm2_kernel(
    const float* __restrict__ hbuf,   // [N][256]
    const float* __restrict__ W2,     // [256][64]
    const float* __restrict__ b2,     // [64]
    float* __restrict__ out)          // [N][64]
{
    __shared__ __align__(16) float hs[MB2][KC2 + 4];   // 64x36 = 9.2KB
    __shared__ __align__(16) float w2s[KC2][D + 4];    // 32x68 = 8.7KB

    const int t = threadIdx.x;
    const int node0 = blockIdx.x * MB2;
    const int tn = t >> 4;    // rows 4tn..4tn+3
    const int td = t & 15;    // cols 4td..4td+3

    float acc[4][4];
    #pragma unroll
    for (int i = 0; i < 4; ++i)
        #pragma unroll
        for (int j = 0; j < 4; ++j) acc[i][j] = 0.f;

    for (int kc = 0; kc < HID; kc += KC2) {
        __syncthreads();
        // stage h chunk [64][32]
        for (int f = t; f < MB2 * 8; f += 256) {
            int n = f >> 3, c = f & 7;
            int node = node0 + n;
            float4 v = make_float4(0.f, 0.f, 0.f, 0.f);
            if (node < N_NODES)
                v = reinterpret_cast<const float4*>(hbuf + (size_t)node * HID + kc)[c];
            *reinterpret_cast<float4*>(&hs[n][c * 4]) = v;
        }
        // stage W2 chunk [32][64]
        for (int f = t; f < KC2 * 16; f += 256) {
            int kk = f >> 4, c = f & 15;
            *reinterpret_cast<float4*>(&w2s[kk][c * 4]) =
                reinterpret_cast<const float4*>(W2 + (size_t)(kc + kk) * D)[c];
        }
        __syncthreads();

        #pragma unroll
        for (int k4 = 0; k4 < KC2; k4 += 4) {
            float4 hv[4];
            #pragma unroll
            for (int i = 0; i < 4; ++i)
                hv[i] = *reinterpret_cast<const float4*>(&hs[4 * tn + i][k4]);
            float4 wv[4];
            #pragma unroll
            for (int kk = 0; kk < 4; ++kk)
                wv[kk] = *reinterpret_cast<const float4*>(&w2s[k4 + kk][4 * td]);
            #pragma unroll
            for (int i = 0; i < 4; ++i) {
                acc[i][0] = fmaf(hv[i].x, wv[0].x, acc[i][0]);
                acc[i][1] = fmaf(hv[i].x, wv[0].y, acc[i][1]);
                acc[i][2] = fmaf(hv[i].x, wv[0].z, acc[i][2]);
                acc[i][3] = fmaf(hv[i].x, wv[0].w, acc[i][3]);
                acc[i][0] = fmaf(hv[i].y, wv[1].x, acc[i][0]);
                acc[i][1] = fmaf(hv[i].y, wv[1].y, acc[i][1]);
                acc[i][2] = fmaf(hv[i].y, wv[1].z, acc[i][2]);
                acc[i][3] = fmaf(hv[i].y, wv[1].w, acc[i][3]);
                acc[i][0] = fmaf(hv[i].z, wv[2].x, acc[i][0]);
                acc[i][1] = fmaf(hv[i].z, wv[2].y, acc[i][1]);
                acc[i][2] = fmaf(hv[i].z, wv[2].z, acc[i][2]);
                acc[i][3] = fmaf(hv[i].z, wv[2].w, acc[i][3]);
                acc[i][0] = fmaf(hv[i].w, wv[3].x, acc[i][0]);
                acc[i][1] = fmaf(hv[i].w, wv[3].y, acc[i][1]);
                acc[i][2] = fmaf(hv[i].w, wv[3].z, acc[i][2]);
                acc[i][3] = fmaf(hv[i].w, wv[3].w, acc[i][3]);
            }
        }
    }

    const float4 bb = *reinterpret_cast<const float4*>(b2 + 4 * td);
    #pragma unroll
    for (int i = 0; i < 4; ++i) {
        const int node = node0 + 4 * tn + i;
        if (node < N_NODES) {
            float4 o = make_float4(acc[i][0] + bb.x, acc[i][1] + bb.y,
                                   acc[i][2] + bb.z, acc[i][3] + bb.w);
            reinterpret_cast<float4*>(out + (size_t)node * D)[td] = o;
        }
    }
}

// ---------------------------------------------------------------------------
// Fallbacks (small ws): atomic scatter + fused MLP from round 3
// ---------------------------------------------------------------------------
__global__ __launch_bounds__(256) void scatter_kernel(
    const float* __restrict__ edges,
    const int* __restrict__ senders,
    const int* __restrict__ receivers,
    float* __restrict__ agg)
{
    int tid = blockIdx.x * 256 + threadIdx.x;
    int e = tid >> 4;
    int c = (tid & 15) << 2;
    if (e >= N_EDGES) return;
    const float4 v = *reinterpret_cast<const float4*>(edges + (long)e * D + c);
    int s = senders[e] * D + c;
    int r = receivers[e] * D + c;
    atomicAdd(&agg[s + 0], v.x); atomicAdd(&agg[s + 1], v.y);
    atomicAdd(&agg[s + 2], v.z); atomicAdd(&agg[s + 3], v.w);
    atomicAdd(&agg[r + 0], v.x); atomicAdd(&agg[r + 1], v.y);
    atomicAdd(&agg[r + 2], v.z); atomicAdd(&agg[r + 3], v.w);
}

__global__ __launch_bounds__(256, 2) void mlp_kernel(
    const float* __restrict__ agg, const float* __restrict__ nodes,
    const float* __restrict__ W1, const float* __restrict__ b1,
    const float* __restrict__ W2, const float* __restrict__ b2,
    float* __restrict__ out)
{
    __shared__ __align__(16) float x_lds[NB][DIN];
    __shared__ __align__(16) float h_lds[NB][HID];
    const int t = threadIdx.x;
    const int node0 = blockIdx.x * NB;

    for (int f = t; f < NB * DIN / 4; f += 256) {
        int n = f >> 5, c = f & 31;
        int node = node0 + n;
        float4 v = make_float4(0.f, 0.f, 0.f, 0.f);
        if (node < N_NODES) {
            const float* src = (c < 16) ? (agg   + (size_t)node * D + c * 4)
                                        : (nodes + (size_t)node * D + (c - 16) * 4);
            v = *reinterpret_cast<const float4*>(src);
        }
        *reinterpret_cast<float4*>(&x_lds[n][c * 4]) = v;
    }
    float w1c[DIN];
    #pragma unroll
    for (int k = 0; k < DIN; ++k) w1c[k] = W1[(size_t)k * HID + t];
    const float bias1 = b1[t];
    __syncthreads();

    for (int n = 0; n < NB; ++n) {
        const float4* xr = reinterpret_cast<const float4*>(x_lds[n]);
        float a0 = 0.f, a1 = 0.f, a2 = 0.f, a3 = 0.f;
        #pragma unroll
        for (int k4 = 0; k4 < 32; ++k4) {
            float4 x = xr[k4];
            a0 = fmaf(w1c[4*k4 + 0], x.x, a0);
            a1 = fmaf(w1c[4*k4 + 1], x.y, a1);
            a2 = fmaf(w1c[4*k4 + 2], x.z, a2);
            a3 = fmaf(w1c[4*k4 + 3], x.w, a3);
        }
        h_lds[n][t] = fmaxf(bias1 + ((a0 + a1) + (a2 + a3)), 0.0f);
    }
    __syncthreads();

    const int d  = t & 63;
    const int ng = t >> 6;
    float acc2[8];
    #pragma unroll
    for (int i = 0; i < 8; ++i) acc2[i] = 0.0f;
    for (int j = 0; j < HID; j += 4) {
        const float w0 = W2[(j + 0) * D + d];
        const float w1 = W2[(j + 1) * D + d];
        const float w2 = W2[(j + 2) * D + d];
        const float w3 = W2[(j + 3) * D + d];
        #pragma unroll
        for (int i = 0; i < 8; ++i) {
            const int n = ng + 4 * i;
            const float4 h4 = *reinterpret_cast<const float4*>(&h_lds[n][j]);
            acc2[i] = fmaf(w0, h4.x, acc2[i]);
            acc2[i] = fmaf(w1, h4.y, acc2[i]);
            acc2[i] = fmaf(w2, h4.z, acc2[i]);
            acc2[i] = fmaf(w3, h4.w, acc2[i]);
        }
    }
    const float bias2 = b2[d];
    #pragma unroll
    for (int i = 0; i < 8; ++i) {
        const int n = ng + 4 * i;
        const int node = node0 + n;
        if (node < N_NODES) out[(size_t)node * D + d] = acc2[i] + bias2;
    }
}

// ---------------------------------------------------------------------------
extern "C" void kernel_launch(void* const* d_in, const int* in_sizes, int n_in,
                              void* d_out, int out_size, void* d_ws, size_t ws_size,
                              hipStream_t stream)
{
    const float* nodes     = (const float*)d_in[0];
    const float* edges     = (const float*)d_in[1];
    const int*   senders   = (const int*)  d_in[2];
    const int*   receivers = (const int*)  d_in[3];
    const float* W1        = (const float*)d_in[4];
    const float* b1        = (const float*)d_in[5];
    const float* W2        = (const float*)d_in[6];
    const float* b2        = (const float*)d_in[7];
    float* out = (float*)d_out;

    // Workspace layout (all 16B-aligned)
    float* agg    = (float*)d_ws;                    // 3,200,000
    int*   deg    = (int*)d_ws + 3200000;            // 50,000
    int*   offs   = deg + 50000;                     // 50,004 (padded)
    int*   cursor = offs + 50004;                    // 50,000
    int*   eidx   = cursor + 50000;                  // 1,600,000
    int*   bsum   = eidx + 1600000;                  // 64
    int*   boff   = bsum + 64;                       // 64
    float* hbuf   = (float*)(boff + 64);             // 12,800,000
    const size_t csr_bytes  = (3200000 + 50000 + 50004 + 50000 + 1600000 + 128) * 4ull;
    const size_t full_bytes = csr_bytes + 12800000ull * 4ull;   // ~71 MB

    const int eb = (N_EDGES + 255) / 256;            // 3125
    const int sb = (N_NODES / 4 + 255) / 256;        // 49 scan blocks
    const int gemm_blocks = (N_NODES + MB1 - 1) / MB1;  // 782

    if (ws_size >= csr_bytes) {
        // ---- CSR counting-sort aggregation ----
        hipMemsetAsync(deg, 0, N_NODES * sizeof(int), stream);
        degree_kernel<<<eb, 256, 0, stream>>>(senders, receivers, deg);
        scan_bsum_kernel<<<sb, 256, 0, stream>>>(deg, bsum);
        scan_boff_kernel<<<1, 64, 0, stream>>>(bsum, boff, &offs[N_NODES], sb);
        scan_write_kernel<<<sb, 256, 0, stream>>>(deg, boff, offs, cursor);
        fill_kernel<<<eb, 256, 0, stream>>>(senders, receivers, cursor, eidx);
        gather_kernel<<<(N_NODES + 3) / 4, 256, 0, stream>>>(edges, offs, eidx, agg);

        if (ws_size >= full_bytes) {
            // ---- split outer-product SGEMMs ----
            gemm1_kernel<<<gemm_blocks, 256, 0, stream>>>(agg, nodes, W1, b1, hbuf);
            gemm2_kernel<<<gemm_blocks, 256, 0, stream>>>(hbuf, W2, b2, out);
        } else {
            mlp_kernel<<<(N_NODES + NB - 1) / NB, 256, 0, stream>>>(
                agg, nodes, W1, b1, W2, b2, out);
        }
    } else {
        // ---- minimal-ws fallback: atomic scatter + fused MLP ----
        hipMemsetAsync(agg, 0, (size_t)N_NODES * D * sizeof(float), stream);
        scatter_kernel<<<(N_EDGES * 16) / 256, 256, 0, stream>>>(edges, senders, receivers, agg);
        mlp_kernel<<<(N_NODES + NB - 1) / NB, 256, 0, stream>>>(
            agg, nodes, W1, b1, W2, b2, out);
    }
}